// Round 1
// 97.077 us; speedup vs baseline: 1.0628x; 1.0628x over previous
//
#include <hip/hip_runtime.h>

// Fused Chamfer loss, N=4, P1=P2=8192, D=3, K=1.
// Single pass over the d2 matrix per batch: rows = pred (16/thread in VGPRs),
// cols = targ staged per 256-tile in LDS as (-2x,-2y,-2z,|y|^2).
// Each pair's full d2 = fma chain onto (|y|^2 + |x|^2) feeds BOTH:
//   - best[k]: row-min (pred->targ, cham_x), written to ws_row[b][seg][row]
//   - ca[jj]:  col-min over the block's 512 rows, flushed per tile through a
//              stride-33 LDS transpose to ws_col[b][rg][col] (rg = 16 groups)
// Reduce kernel: dir0 = min over nseg of ws_row, dir1 = min over 16 rg of
// ws_col (p < L), clamp, scale, block-sum, atomicAdd.
constexpr int N = 4;
constexpr int P = 8192;
constexpr int TILE = 256;          // cols staged in LDS per iter
constexpr int MI = 16;             // rows per thread
constexpr int ROWS = 512;          // rows per block (32 rowtiles * MI)
constexpr int RG = P / ROWS;       // 16 row groups
constexpr float BIGV = 1e30f;

__global__ __launch_bounds__(256) void chamfer_min_kernel(
    const float* __restrict__ pred, const float* __restrict__ targ,
    const int* __restrict__ lens, float* __restrict__ ws)
{
    const int nseg = gridDim.y;
    const int segc = P / nseg;
    const int seg  = blockIdx.y;
    const int b    = blockIdx.x >> 4;          // RG = 16
    const int rg   = blockIdx.x & (RG - 1);
    const int row0 = rg * ROWS;
    const int c0   = seg * segc;
    const int L    = lens[b];
    const int tid  = threadIdx.x;
    const int ch   = tid >> 5;                 // 0..7: 32-col slice of tile
    const int rt   = tid & 31;

    float* wcol = ws + ((size_t)b * RG + rg) * P;
    float* wrow = ws + (size_t)N * RG * P + ((size_t)b * nseg + seg) * P + row0;

    if (c0 >= L) {     // no valid cols in this segment: row sentinel, cols unread
        wrow[tid] = BIGV; wrow[tid + 256] = BIGV;
        return;
    }

    const float* rbase = pred + (size_t)b * P * 3;
    const float* cbase = targ + (size_t)b * P * 3;

    float rx[MI], ry[MI], rz[MI], pw[MI], best[MI];
    #pragma unroll
    for (int k = 0; k < MI; ++k) {
        const float* p = rbase + (size_t)(row0 + rt + 32 * k) * 3;
        rx[k] = p[0]; ry[k] = p[1]; rz[k] = p[2];
        pw[k] = fmaf(rx[k], rx[k], fmaf(ry[k], ry[k], rz[k] * rz[k]));
        best[k] = BIGV;
    }

    __shared__ float4 sy[TILE];
    __shared__ float  scr[TILE * 33];   // col flush transpose; aliased as row-red

    const int vc = (L - c0 < segc) ? (L - c0) : segc;
    const int nt = (vc + TILE - 1) / TILE;

    // prefetch tile 0 column into registers
    float ax = 0.f, ay = 0.f, az = 0.f;
    int cvalid;
    {
        const int col = c0 + tid;
        cvalid = (col < L);
        const float* p = cbase + (size_t)col * 3;
        if (cvalid) { ax = p[0]; ay = p[1]; az = p[2]; }
    }

    for (int t = 0; t < nt; ++t) {
        const float4 cv = cvalid
            ? make_float4(-2.f * ax, -2.f * ay, -2.f * az,
                          fmaf(ax, ax, fmaf(ay, ay, az * az)))
            : make_float4(0.f, 0.f, 0.f, BIGV);   // never wins either min
        __syncthreads();                           // scr/sy consumers done
        sy[tid] = cv;
        __syncthreads();

        if (t + 1 < nt) {    // issue next tile's loads under this tile's compute
            const int col = c0 + (t + 1) * TILE + tid;
            cvalid = (col < L);
            if (cvalid) {
                const float* p = cbase + (size_t)col * 3;
                ax = p[0]; ay = p[1]; az = p[2];
            }
        }

        const float4* sp = &sy[ch * 32];
        float ca[32];
        #pragma unroll
        for (int j = 0; j < 32; ++j) ca[j] = BIGV;

        #pragma unroll
        for (int jj = 0; jj < 32; jj += 2) {
            const float4 q0 = sp[jj];
            const float4 q1 = sp[jj + 1];
            float m0 = BIGV, m1 = BIGV;
            #pragma unroll
            for (int k = 0; k < MI; k += 2) {
                const float e0a = fmaf(rx[k],   q0.x, fmaf(ry[k],   q0.y, fmaf(rz[k],   q0.z, q0.w + pw[k])));
                const float e0b = fmaf(rx[k+1], q0.x, fmaf(ry[k+1], q0.y, fmaf(rz[k+1], q0.z, q0.w + pw[k+1])));
                const float e1a = fmaf(rx[k],   q1.x, fmaf(ry[k],   q1.y, fmaf(rz[k],   q1.z, q1.w + pw[k])));
                const float e1b = fmaf(rx[k+1], q1.x, fmaf(ry[k+1], q1.y, fmaf(rz[k+1], q1.z, q1.w + pw[k+1])));
                best[k]   = fminf(best[k],   fminf(e0a, e1a));   // -> v_min3
                best[k+1] = fminf(best[k+1], fminf(e0b, e1b));
                m0 = fminf(m0, fminf(e0a, e0b));                  // col partial
                m1 = fminf(m1, fminf(e1a, e1b));
            }
            ca[jj]     = fminf(ca[jj],     m0);
            ca[jj + 1] = fminf(ca[jj + 1], m1);
        }

        // flush col partials: transpose via LDS, stride 33 => conflict-free
        #pragma unroll
        for (int j = 0; j < 32; ++j)
            scr[(ch * 32 + j) * 33 + rt] = ca[j];
        __syncthreads();
        {
            const float* r = &scr[tid * 33];   // 32 rowtile partials for col tid
            float v = BIGV;
            #pragma unroll
            for (int i = 0; i < 32; i += 4)
                v = fminf(v, fminf(fminf(r[i], r[i+1]), fminf(r[i+2], r[i+3])));
            wcol[c0 + t * TILE + tid] = v;     // cols >= L carry BIGV: unread
        }
    }

    // row epilogue: 8-way chunk min per row (stride 9 => 2-way, free)
    __syncthreads();
    #pragma unroll
    for (int k = 0; k < MI; ++k)
        scr[(rt + 32 * k) * 9 + ch] = best[k];
    __syncthreads();
    #pragma unroll
    for (int r2 = 0; r2 < 2; ++r2) {
        const int row = tid + r2 * 256;
        const float* r = &scr[row * 9];
        wrow[row] = fminf(fminf(fminf(r[0], r[1]), fminf(r[2], r[3])),
                          fminf(fminf(r[4], r[5]), fminf(r[6], r[7])));
    }
}

__global__ __launch_bounds__(256) void chamfer_reduce_kernel(
    const float* __restrict__ ws, const int* __restrict__ lens,
    float* __restrict__ out, int nseg)
{
    const int item = blockIdx.x * 256 + threadIdx.x;     // 2*N*P = 65536
    const int dir = item >> 15;
    const int b   = (item >> 13) & (N - 1);
    const int p   = item & (P - 1);
    const int L   = lens[b];

    float c = 0.f;
    if (dir == 0) {        // pred->targ row mins
        const float* base = ws + (size_t)N * RG * P + (size_t)b * nseg * P + p;
        float v = BIGV;
        if (nseg == 16) {
            #pragma unroll
            for (int s = 0; s < 16; ++s) v = fminf(v, base[(size_t)s * P]);
        } else {
            #pragma unroll
            for (int s = 0; s < 8; ++s) v = fminf(v, base[(size_t)s * P]);
        }
        c = fmaxf(v, 0.f) * (1.0f / ((float)P * (float)N));
    } else if (p < L) {    // targ->pred col mins
        const float* base = ws + (size_t)b * RG * P + p;
        float v = BIGV;
        #pragma unroll
        for (int g = 0; g < RG; ++g) v = fminf(v, base[(size_t)g * P]);
        c = fmaxf(v, 0.f) / ((float)L * (float)N);
    }
    #pragma unroll
    for (int off = 32; off; off >>= 1) c += __shfl_down(c, off, 64);
    __shared__ float acc[4];
    if ((threadIdx.x & 63) == 0) acc[threadIdx.x >> 6] = c;
    __syncthreads();
    if (threadIdx.x == 0) atomicAdd(out, acc[0] + acc[1] + acc[2] + acc[3]);
}

extern "C" void kernel_launch(void* const* d_in, const int* in_sizes, int n_in,
                              void* d_out, int out_size, void* d_ws, size_t ws_size,
                              hipStream_t stream)
{
    const float* pred = (const float*)d_in[0];
    const float* targ = (const float*)d_in[1];
    const int*   lens = (const int*)d_in[2];
    float* out = (float*)d_out;
    float* ws  = (float*)d_ws;

    // ws: col partials N*RG*P (2 MB) + row partials N*nseg*P (2 MB @ nseg=16).
    const size_t colb = (size_t)N * RG * P * sizeof(float);
    const int nseg = (ws_size >= colb + (size_t)N * 16 * P * sizeof(float)) ? 16 : 8;

    hipMemsetAsync(out, 0, out_size * sizeof(float), stream);
    dim3 grid(N * RG, nseg);                   // 64 x nseg blocks
    chamfer_min_kernel<<<grid, 256, 0, stream>>>(pred, targ, lens, ws);
    chamfer_reduce_kernel<<<(2 * N * P) / 256, 256, 0, stream>>>(ws, lens, out, nseg);
}